// Round 1
// baseline (880.095 us; speedup 1.0000x reference)
//
#include <hip/hip_runtime.h>

typedef unsigned short ushort_t;
typedef __attribute__((ext_vector_type(8))) __bf16 bf16x8;
typedef __attribute__((ext_vector_type(4))) float f32x4;

__device__ __forceinline__ ushort_t f2bf(float f) {
  unsigned u = __float_as_uint(f);
  u = u + 0x7FFFu + ((u >> 16) & 1u);   // round-to-nearest-even
  return (ushort_t)(u >> 16);
}
__device__ __forceinline__ float bf2f(ushort_t h) {
  return __uint_as_float(((unsigned)h) << 16);
}

// async global->LDS, 16B per lane. LDS dest = wave-uniform base + lane*16.
__device__ __forceinline__ void async_copy16(ushort_t* lds, const ushort_t* g) {
  __builtin_amdgcn_global_load_lds(
      (__attribute__((address_space(1))) void*)const_cast<ushort_t*>(g),
      (__attribute__((address_space(3))) void*)lds, 16, 0, 0);
}

// ---------------- conversion / prep kernels ----------------

__global__ __launch_bounds__(256) void cvt_bf16_k(const float* __restrict__ in,
                                                  ushort_t* __restrict__ outp, int n4) {
  int i = blockIdx.x * blockDim.x + threadIdx.x;
  if (i >= n4) return;
  float4 v = ((const float4*)in)[i];
  ushort4 o;
  o.x = f2bf(v.x); o.y = f2bf(v.y); o.z = f2bf(v.z); o.w = f2bf(v.w);
  ((ushort4*)outp)[i] = o;
}

// W[Kd][Nd] f32 -> Wt[Nd][Kd] bf16
__global__ __launch_bounds__(256) void transpose_k(const float* __restrict__ W,
                                                   ushort_t* __restrict__ Wt, int Kd, int Nd) {
  __shared__ float tile[32][33];
  int n0 = blockIdx.x * 32, k0 = blockIdx.y * 32;
  int tx = threadIdx.x, ty = threadIdx.y;   // (32,8)
#pragma unroll
  for (int i = 0; i < 4; i++)
    tile[ty + i * 8][tx] = W[(size_t)(k0 + ty + i * 8) * Nd + n0 + tx];
  __syncthreads();
#pragma unroll
  for (int i = 0; i < 4; i++)
    Wt[(size_t)(n0 + ty + i * 8) * Kd + k0 + tx] = f2bf(tile[tx][ty + i * 8]);
}

// codebook [4096][256]: bf16 copy + fp32 row norms
__global__ __launch_bounds__(256) void cvt_codebook_k(const float* __restrict__ cb,
                                                      ushort_t* __restrict__ cbb,
                                                      float* __restrict__ cnorm) {
  int j = blockIdx.x, t = threadIdx.x;
  float c = cb[j * 256 + t];
  cbb[j * 256 + t] = f2bf(c);
  float s = c * c;
  for (int o = 32; o; o >>= 1) s += __shfl_down(s, o);
  __shared__ float red[4];
  if ((t & 63) == 0) red[t >> 6] = s;
  __syncthreads();
  if (t == 0) cnorm[j] = red[0] + red[1] + red[2] + red[3];
}

// ---------------- main MFMA GEMM ----------------
// C = A(MxK,bf16 rowmajor) * Bt(NxK,bf16 rowmajor)^T, fp32 acc, fused epilogue.
// EPI: 0=bias+BN+ReLU->OutA | 1=bias->OutA,relu->OutB | 2=res+BN(bias)->OutA,relu->OutB
//      4=res+BN(bias)->OutA | 5=bias+sigmoid->OutF | 6=VQ argmin (cnorm,keys)
template <int EPI>
__global__ __launch_bounds__(256, 2) void gemm_k(
    const ushort_t* __restrict__ A, const ushort_t* __restrict__ Bt,
    int M, int N, int K,
    const float* __restrict__ bias,
    const float* __restrict__ bng, const float* __restrict__ bnbeta,
    const float* __restrict__ bnm, const float* __restrict__ bnv,
    const ushort_t* __restrict__ Res,
    ushort_t* __restrict__ OutA, ushort_t* __restrict__ OutB,
    float* __restrict__ OutF,
    const float* __restrict__ cnorm, unsigned long long* __restrict__ keys) {
  __shared__ alignas(16) ushort_t As[128 * 64];
  __shared__ alignas(16) ushort_t Bs[128 * 64];
  const int tid = threadIdx.x;
  const int wave = tid >> 6, lane = tid & 63;
  const int quad = lane >> 4, l16 = lane & 15;
  const int wm = wave >> 1, wn = wave & 1;
  const int m0 = blockIdx.y * 128, n0 = blockIdx.x * 128;

  f32x4 acc[4][4];
#pragma unroll
  for (int i = 0; i < 4; i++)
#pragma unroll
    for (int j = 0; j < 4; j++) acc[i][j] = f32x4{0.f, 0.f, 0.f, 0.f};

  // staging geometry: inst i covers rows i*32 + wave*8 + lane/8, chunk (lane&7)^(row&7)
  const int srow = (wave << 3) + (lane >> 3);           // row within the 32-row group
  const int schunk = (lane & 7) ^ (lane >> 3);          // XOR-swizzled 8-elem chunk
  const long aoff = (long)(m0 + srow) * K + (schunk << 3);
  const long boff = (long)(n0 + srow) * K + (schunk << 3);

  for (int k0 = 0; k0 < K; k0 += 64) {
#pragma unroll
    for (int i = 0; i < 4; i++) {
      async_copy16(&As[(i * 32 + wave * 8) * 64], A + aoff + (long)i * 32 * K + k0);
      async_copy16(&Bs[(i * 32 + wave * 8) * 64], Bt + boff + (long)i * 32 * K + k0);
    }
    __syncthreads();   // compiler drains vmcnt before s_barrier
#pragma unroll
    for (int kk = 0; kk < 2; kk++) {
      bf16x8 af[4], bfr[4];
#pragma unroll
      for (int i = 0; i < 4; i++) {
        const int ca = ((kk * 4 + quad) ^ (l16 & 7)) << 3;   // de-swizzle
        af[i] = *(const bf16x8*)&As[(wm * 64 + i * 16 + l16) * 64 + ca];
        bfr[i] = *(const bf16x8*)&Bs[(wn * 64 + i * 16 + l16) * 64 + ca];
      }
#pragma unroll
      for (int i = 0; i < 4; i++)
#pragma unroll
        for (int j = 0; j < 4; j++)
          acc[i][j] = __builtin_amdgcn_mfma_f32_16x16x32_bf16(af[i], bfr[j], acc[i][j], 0, 0, 0);
    }
    __syncthreads();
  }

  if constexpr (EPI == 6) {
    // score_j = |c_j|^2 - 2*z.c_j  (row-constant |z|^2 dropped); argmin w/ lowest-index ties
#pragma unroll
    for (int i = 0; i < 4; i++) {
#pragma unroll
      for (int r = 0; r < 4; r++) {
        int row = m0 + wm * 64 + i * 16 + quad * 4 + r;
        unsigned long long best = ~0ull;
#pragma unroll
        for (int j = 0; j < 4; j++) {
          int col = n0 + wn * 64 + j * 16 + l16;
          float sc = cnorm[col] - 2.f * acc[i][j][r];
          unsigned ub = __float_as_uint(sc);
          ub = (ub & 0x80000000u) ? ~ub : (ub | 0x80000000u);   // sortable float
          unsigned long long key = ((unsigned long long)ub << 32) | (unsigned)col;
          if (key < best) best = key;
        }
#pragma unroll
        for (int o = 1; o < 16; o <<= 1) {
          unsigned long long other = __shfl_xor(best, o, 16);
          if (other < best) best = other;
        }
        if (l16 == 0) atomicMin(&keys[row], best);
      }
    }
    return;
  } else {
    constexpr bool HAS_BN = (EPI == 0 || EPI == 2 || EPI == 4);
    constexpr bool HAS_RES = (EPI == 2 || EPI == 4);
#pragma unroll
    for (int j = 0; j < 4; j++) {
      int col = n0 + wn * 64 + j * 16 + l16;
      float bi = bias[col];
      float sA = 1.f, sB = 0.f;
      if constexpr (HAS_BN) {
        float s = rsqrtf(bnv[col] + 1e-5f);
        sA = bng[col] * s;
        sB = bnbeta[col] - bnm[col] * sA;
      }
#pragma unroll
      for (int i = 0; i < 4; i++) {
#pragma unroll
        for (int r = 0; r < 4; r++) {
          long row = m0 + wm * 64 + i * 16 + quad * 4 + r;
          float t = acc[i][j][r] + bi;
          if constexpr (HAS_BN) t = t * sA + sB;
          if constexpr (HAS_RES) t += bf2f(Res[row * N + col]);
          long o = row * N + col;
          if constexpr (EPI == 0) OutA[o] = f2bf(fmaxf(t, 0.f));
          if constexpr (EPI == 1 || EPI == 2) {
            OutA[o] = f2bf(t);
            OutB[o] = f2bf(fmaxf(t, 0.f));
          }
          if constexpr (EPI == 4) OutA[o] = f2bf(t);
          if constexpr (EPI == 5) OutF[o] = 1.f / (1.f + expf(-t));
        }
      }
    }
  }
}

// ---------------- VQ gather / loss partials / histogram ----------------
__global__ __launch_bounds__(256) void vq_finalize_k(
    const unsigned long long* __restrict__ keys, const float* __restrict__ cb,
    const ushort_t* __restrict__ zb, ushort_t* __restrict__ hq, ushort_t* __restrict__ hqr,
    float* __restrict__ hist, float* __restrict__ partial) {
  int row = blockIdx.x, t = threadIdx.x;
  unsigned long long k = keys[row];
  int j = (int)(k & 0xffffffffull);
  float q = cb[j * 256 + t];
  float z = bf2f(zb[(size_t)row * 256 + t]);
  float d = (q - z) * (q - z);
  for (int o = 32; o; o >>= 1) d += __shfl_down(d, o);
  __shared__ float red[4];
  if ((t & 63) == 0) red[t >> 6] = d;
  __syncthreads();
  hq[(size_t)row * 256 + t] = f2bf(q);
  hqr[(size_t)row * 256 + t] = f2bf(fmaxf(q, 0.f));
  if (t == 0) {
    partial[row] = red[0] + red[1] + red[2] + red[3];
    atomicAdd(&hist[j], 1.0f);
  }
}

__global__ __launch_bounds__(256) void finalize_out_k(const float* __restrict__ hist,
                                                      const float* __restrict__ partial,
                                                      float* __restrict__ out) {
  int t = threadIdx.x;
  float ls = 0.f, e = 0.f;
  for (int i = t; i < 16384; i += 256) ls += partial[i];
  for (int i = t; i < 4096; i += 256) {
    float p = hist[i] * (1.f / 16384.f);
    e += p * logf(p + 1e-10f);
  }
  for (int o = 32; o; o >>= 1) {
    ls += __shfl_down(ls, o);
    e += __shfl_down(e, o);
  }
  __shared__ float r1[4], r2[4];
  if ((t & 63) == 0) { r1[t >> 6] = ls; r2[t >> 6] = e; }
  __syncthreads();
  if (t == 0) {
    // loss = (1+CC)*mean((q-z)^2); stop_gradient makes both terms equal in value
    out[0] = (r1[0] + r1[1] + r1[2] + r1[3]) * (1.25f / 4194304.f);
    out[1 + 33554432] = expf(-(r2[0] + r2[1] + r2[2] + r2[3]));
  }
}

// ---------------- launch ----------------
extern "C" void kernel_launch(void* const* d_in, const int* in_sizes, int n_in,
                              void* d_out, int out_size, void* d_ws, size_t ws_size,
                              hipStream_t stream) {
  (void)in_sizes; (void)n_in; (void)out_size; (void)ws_size;
  const float* x    = (const float*)d_in[0];
  const float* W1   = (const float*)d_in[1];
  const float* b1   = (const float*)d_in[2];
  const float* bn1g = (const float*)d_in[3];
  const float* bn1b = (const float*)d_in[4];
  const float* bn1m = (const float*)d_in[5];
  const float* bn1v = (const float*)d_in[6];
  const float* W2   = (const float*)d_in[7];
  const float* b2   = (const float*)d_in[8];
  const float* rbW  = (const float*)d_in[9];
  const float* rbB  = (const float*)d_in[10];
  const float* rbG  = (const float*)d_in[11];
  const float* rbBe = (const float*)d_in[12];
  const float* rbM  = (const float*)d_in[13];
  const float* rbV  = (const float*)d_in[14];
  const float* cb   = (const float*)d_in[15];
  const float* decW = (const float*)d_in[16];
  const float* decB = (const float*)d_in[17];
  float* out = (float*)d_out;

  char* w = (char*)d_ws;
  size_t off = 0;
  auto take = [&](size_t bytes) -> char* {
    char* p = w + off;
    off += (bytes + 255) & ~((size_t)255);
    return p;
  };
  ushort_t* xb    = (ushort_t*)take((size_t)4096 * 8192 * 2);
  ushort_t* w1t   = (ushort_t*)take((size_t)1024 * 8192 * 2);
  ushort_t* w2t   = (ushort_t*)take((size_t)1024 * 1024 * 2);
  ushort_t* rbwt  = (ushort_t*)take((size_t)5 * 1024 * 1024 * 2);
  ushort_t* decwt = (ushort_t*)take((size_t)8192 * 1024 * 2);
  ushort_t* cbb   = (ushort_t*)take((size_t)4096 * 256 * 2);
  float* cnorm    = (float*)take(4096 * 4);
  unsigned long long* keys = (unsigned long long*)take(16384 * 8);
  float* hist     = (float*)take(4096 * 4);
  float* partial  = (float*)take(16384 * 4);
  ushort_t* bufA  = (ushort_t*)take((size_t)4096 * 1024 * 2);
  ushort_t* bufB  = (ushort_t*)take((size_t)4096 * 1024 * 2);
  ushort_t* bufC  = (ushort_t*)take((size_t)4096 * 1024 * 2);
  ushort_t* bufD  = (ushort_t*)take((size_t)4096 * 1024 * 2);

  (void)hipMemsetAsync(keys, 0xFF, 16384 * 8, stream);
  (void)hipMemsetAsync(hist, 0, 4096 * 4, stream);

  // prep: bf16 conversions (+ weight transposes to [N][K])
  cvt_bf16_k<<<32768, 256, 0, stream>>>(x, xb, 33554432 / 4);
  transpose_k<<<dim3(32, 256), dim3(32, 8), 0, stream>>>(W1, w1t, 8192, 1024);
  transpose_k<<<dim3(32, 32), dim3(32, 8), 0, stream>>>(W2, w2t, 1024, 1024);
  for (int i = 0; i < 5; i++)
    transpose_k<<<dim3(32, 32), dim3(32, 8), 0, stream>>>(
        rbW + (size_t)i * 1024 * 1024, rbwt + (size_t)i * 1024 * 1024, 1024, 1024);
  transpose_k<<<dim3(256, 32), dim3(32, 8), 0, stream>>>(decW, decwt, 1024, 8192);
  cvt_codebook_k<<<4096, 256, 0, stream>>>(cb, cbb, cnorm);

  const ushort_t* nu = nullptr;
  ushort_t* nuo = nullptr;
  const float* nf = nullptr;
  float* nfo = nullptr;
  unsigned long long* nk = nullptr;

  // G1: h1 = relu(bn1(x@W1 + b1))           -> bufA
  gemm_k<0><<<dim3(8, 32), 256, 0, stream>>>(xb, w1t, 4096, 1024, 8192, b1, bn1g, bn1b,
                                             bn1m, bn1v, nu, bufA, nuo, nfo, nf, nk);
  // G2: h2 = h1@W2 + b2                     -> bufB (raw), bufC (relu)
  gemm_k<1><<<dim3(8, 32), 256, 0, stream>>>(bufA, w2t, 4096, 1024, 1024, b2, nf, nf, nf,
                                             nf, nu, bufB, bufC, nfo, nf, nk);
  // G3: z1 = h2 + bn0(relu(h2)@W0 + b0)     -> bufA (raw), bufD (relu)
  gemm_k<2><<<dim3(8, 32), 256, 0, stream>>>(bufC, rbwt, 4096, 1024, 1024, rbB, rbG, rbBe,
                                             rbM, rbV, bufB, bufA, bufD, nfo, nf, nk);
  // G4: z  = z1 + bn1(relu(z1)@W1 + b1)     -> bufB
  gemm_k<4><<<dim3(8, 32), 256, 0, stream>>>(bufD, rbwt + 1 * 1048576, 4096, 1024, 1024,
                                             rbB + 1024, rbG + 1024, rbBe + 1024, rbM + 1024,
                                             rbV + 1024, bufA, bufB, nuo, nfo, nf, nk);
  // VQ: argmin_j |z_i - c_j|^2 over flat [16384 x 256]
  gemm_k<6><<<dim3(32, 128), 256, 0, stream>>>(bufB, cbb, 16384, 4096, 256, nf, nf, nf, nf,
                                               nf, nu, nuo, nuo, nfo, cnorm, keys);
  // gather + loss partials + histogram      -> bufC (hq), bufD (relu hq)
  vq_finalize_k<<<16384, 256, 0, stream>>>(keys, cb, bufB, bufC, bufD, hist, partial);
  // G5: d1 = hq + bn2(relu(hq)@W2 + b2)     -> bufA (raw), bufB (relu)
  gemm_k<2><<<dim3(8, 32), 256, 0, stream>>>(bufD, rbwt + 2 * 1048576, 4096, 1024, 1024,
                                             rbB + 2048, rbG + 2048, rbBe + 2048, rbM + 2048,
                                             rbV + 2048, bufC, bufA, bufB, nfo, nf, nk);
  // G6: d2                                   -> bufC (raw), bufD (relu)
  gemm_k<2><<<dim3(8, 32), 256, 0, stream>>>(bufB, rbwt + 3 * 1048576, 4096, 1024, 1024,
                                             rbB + 3072, rbG + 3072, rbBe + 3072, rbM + 3072,
                                             rbV + 3072, bufA, bufC, bufD, nfo, nf, nk);
  // G7: d3                                   -> bufA
  gemm_k<4><<<dim3(8, 32), 256, 0, stream>>>(bufD, rbwt + 4 * 1048576, 4096, 1024, 1024,
                                             rbB + 4096, rbG + 4096, rbBe + 4096, rbM + 4096,
                                             rbV + 4096, bufC, bufA, nuo, nfo, nf, nk);
  // G8: x_recon = sigmoid(d3@decW + decB)   -> out[1..]
  gemm_k<5><<<dim3(64, 32), 256, 0, stream>>>(bufA, decwt, 4096, 8192, 1024, decB, nf, nf,
                                              nf, nf, nu, nuo, nuo, out + 1, nf, nk);
  // loss (out[0]) and perplexity (out[33554433])
  finalize_out_k<<<1, 256, 0, stream>>>(hist, partial, out);
}

// Round 2
// 790.586 us; speedup vs baseline: 1.1132x; 1.1132x over previous
//
#include <hip/hip_runtime.h>

typedef unsigned short ushort_t;
typedef __attribute__((ext_vector_type(8))) __bf16 bf16x8;
typedef __attribute__((ext_vector_type(4))) float f32x4;

__device__ __forceinline__ ushort_t f2bf(float f) {
  unsigned u = __float_as_uint(f);
  u = u + 0x7FFFu + ((u >> 16) & 1u);   // round-to-nearest-even
  return (ushort_t)(u >> 16);
}
__device__ __forceinline__ float bf2f(ushort_t h) {
  return __uint_as_float(((unsigned)h) << 16);
}

// async global->LDS, 16B per lane. LDS dest = wave-uniform base + lane*16.
__device__ __forceinline__ void async_copy16(ushort_t* lds, const ushort_t* g) {
  __builtin_amdgcn_global_load_lds(
      (__attribute__((address_space(1))) void*)const_cast<ushort_t*>(g),
      (__attribute__((address_space(3))) void*)lds, 16, 0, 0);
}

// ---------------- conversion / prep kernels ----------------

__global__ __launch_bounds__(256) void cvt_bf16_k(const float* __restrict__ in,
                                                  ushort_t* __restrict__ outp, int n4) {
  int i = blockIdx.x * blockDim.x + threadIdx.x;
  if (i >= n4) return;
  float4 v = ((const float4*)in)[i];
  ushort4 o;
  o.x = f2bf(v.x); o.y = f2bf(v.y); o.z = f2bf(v.z); o.w = f2bf(v.w);
  ((ushort4*)outp)[i] = o;
}

// W[Kd][Nd] f32 -> Wt[Nd][Kd] bf16
__global__ __launch_bounds__(256) void transpose_k(const float* __restrict__ W,
                                                   ushort_t* __restrict__ Wt, int Kd, int Nd) {
  __shared__ float tile[32][33];
  int n0 = blockIdx.x * 32, k0 = blockIdx.y * 32;
  int tx = threadIdx.x, ty = threadIdx.y;   // (32,8)
#pragma unroll
  for (int i = 0; i < 4; i++)
    tile[ty + i * 8][tx] = W[(size_t)(k0 + ty + i * 8) * Nd + n0 + tx];
  __syncthreads();
#pragma unroll
  for (int i = 0; i < 4; i++)
    Wt[(size_t)(n0 + ty + i * 8) * Kd + k0 + tx] = f2bf(tile[tx][ty + i * 8]);
}

// codebook [4096][256]: bf16 copy + fp32 row norms
__global__ __launch_bounds__(256) void cvt_codebook_k(const float* __restrict__ cb,
                                                      ushort_t* __restrict__ cbb,
                                                      float* __restrict__ cnorm) {
  int j = blockIdx.x, t = threadIdx.x;
  float c = cb[j * 256 + t];
  cbb[j * 256 + t] = f2bf(c);
  float s = c * c;
  for (int o = 32; o; o >>= 1) s += __shfl_down(s, o);
  __shared__ float red[4];
  if ((t & 63) == 0) red[t >> 6] = s;
  __syncthreads();
  if (t == 0) cnorm[j] = red[0] + red[1] + red[2] + red[3];
}

// ---------------- main MFMA GEMM ----------------
// C = A(MxK,bf16 rowmajor) * Bt(NxK,bf16 rowmajor)^T, fp32 acc, fused epilogue.
// Tile TMxTN (multiples of 32), 2x2 waves, 16x16x32 MFMA frags.
// EPI: 1=bias->OutA,relu->OutB | 2=res+BN(bias)->OutA,relu->OutB | 4=res+BN(bias)->OutA
//      5=bias+sigmoid->OutF | 6=VQ argmin (cnorm,keys) | 7=raw f32 partial (split-K)
template <int EPI, int TM, int TN>
__global__ __launch_bounds__(256, 4) void gemm_k(
    const ushort_t* __restrict__ A, const ushort_t* __restrict__ Bt,
    int M, int N, int K, int KS,
    const float* __restrict__ bias,
    const float* __restrict__ bng, const float* __restrict__ bnbeta,
    const float* __restrict__ bnm, const float* __restrict__ bnv,
    const ushort_t* __restrict__ Res,
    ushort_t* __restrict__ OutA, ushort_t* __restrict__ OutB,
    float* __restrict__ OutF,
    const float* __restrict__ cnorm, unsigned long long* __restrict__ keys) {
  constexpr int FI = TM / 32, FJ = TN / 32;   // frags per wave (2x2 wave grid)
  __shared__ alignas(16) ushort_t As[TM * 64];
  __shared__ alignas(16) ushort_t Bs[TN * 64];
  const int tid = threadIdx.x;
  const int wave = tid >> 6, lane = tid & 63;
  const int quad = lane >> 4, l16 = lane & 15;
  const int wm = wave >> 1, wn = wave & 1;
  const int m0 = blockIdx.y * TM, n0 = blockIdx.x * TN;

  f32x4 acc[FI][FJ];
#pragma unroll
  for (int i = 0; i < FI; i++)
#pragma unroll
    for (int j = 0; j < FJ; j++) acc[i][j] = f32x4{0.f, 0.f, 0.f, 0.f};

  // staging geometry: inst i covers rows i*32 + wave*8 + lane/8, chunk (lane&7)^(row&7)
  const int srow = (wave << 3) + (lane >> 3);           // row within the 32-row group
  const int schunk = (lane & 7) ^ (lane >> 3);          // XOR-swizzled 8-elem chunk
  const long aoff = (long)(m0 + srow) * K + (schunk << 3);
  const long boff = (long)(n0 + srow) * K + (schunk << 3);

  const int kbeg = blockIdx.z * KS, kend = kbeg + KS;
  for (int k0 = kbeg; k0 < kend; k0 += 64) {
#pragma unroll
    for (int i = 0; i < TM / 32; i++)
      async_copy16(&As[(i * 32 + wave * 8) * 64], A + aoff + (long)i * 32 * K + k0);
#pragma unroll
    for (int i = 0; i < TN / 32; i++)
      async_copy16(&Bs[(i * 32 + wave * 8) * 64], Bt + boff + (long)i * 32 * K + k0);
    __syncthreads();   // compiler drains vmcnt before s_barrier
#pragma unroll
    for (int kk = 0; kk < 2; kk++) {
      bf16x8 af[FI], bfr[FJ];
      const int ca = ((kk * 4 + quad) ^ (l16 & 7)) << 3;   // de-swizzle
#pragma unroll
      for (int i = 0; i < FI; i++)
        af[i] = *(const bf16x8*)&As[(wm * (TM / 2) + i * 16 + l16) * 64 + ca];
#pragma unroll
      for (int j = 0; j < FJ; j++)
        bfr[j] = *(const bf16x8*)&Bs[(wn * (TN / 2) + j * 16 + l16) * 64 + ca];
#pragma unroll
      for (int i = 0; i < FI; i++)
#pragma unroll
        for (int j = 0; j < FJ; j++)
          acc[i][j] = __builtin_amdgcn_mfma_f32_16x16x32_bf16(af[i], bfr[j], acc[i][j], 0, 0, 0);
    }
    __syncthreads();
  }

  if constexpr (EPI == 6) {
    // score_j = |c_j|^2 - 2*z.c_j  (row-constant |z|^2 dropped); argmin w/ lowest-index ties
#pragma unroll
    for (int i = 0; i < FI; i++) {
#pragma unroll
      for (int r = 0; r < 4; r++) {
        int row = m0 + wm * (TM / 2) + i * 16 + quad * 4 + r;
        unsigned long long best = ~0ull;
#pragma unroll
        for (int j = 0; j < FJ; j++) {
          int col = n0 + wn * (TN / 2) + j * 16 + l16;
          float sc = cnorm[col] - 2.f * acc[i][j][r];
          unsigned ub = __float_as_uint(sc);
          ub = (ub & 0x80000000u) ? ~ub : (ub | 0x80000000u);   // sortable float
          unsigned long long key = ((unsigned long long)ub << 32) | (unsigned)col;
          if (key < best) best = key;
        }
#pragma unroll
        for (int o = 1; o < 16; o <<= 1) {
          unsigned long long other = __shfl_xor(best, o, 16);
          if (other < best) best = other;
        }
        if (l16 == 0) atomicMin(&keys[row], best);
      }
    }
    return;
  } else if constexpr (EPI == 7) {
    float* dst = OutF + (size_t)blockIdx.z * (size_t)M * N;
#pragma unroll
    for (int j = 0; j < FJ; j++) {
      int col = n0 + wn * (TN / 2) + j * 16 + l16;
#pragma unroll
      for (int i = 0; i < FI; i++)
#pragma unroll
        for (int r = 0; r < 4; r++) {
          long row = m0 + wm * (TM / 2) + i * 16 + quad * 4 + r;
          dst[row * N + col] = acc[i][j][r];
        }
    }
  } else {
    constexpr bool HAS_BN = (EPI == 2 || EPI == 4);
    constexpr bool HAS_RES = (EPI == 2 || EPI == 4);
#pragma unroll
    for (int j = 0; j < FJ; j++) {
      int col = n0 + wn * (TN / 2) + j * 16 + l16;
      float bi = bias[col];
      float sA = 1.f, sB = 0.f;
      if constexpr (HAS_BN) {
        float s = rsqrtf(bnv[col] + 1e-5f);
        sA = bng[col] * s;
        sB = bnbeta[col] - bnm[col] * sA;
      }
#pragma unroll
      for (int i = 0; i < FI; i++) {
#pragma unroll
        for (int r = 0; r < 4; r++) {
          long row = m0 + wm * (TM / 2) + i * 16 + quad * 4 + r;
          float t = acc[i][j][r] + bi;
          if constexpr (HAS_BN) t = t * sA + sB;
          if constexpr (HAS_RES) t += bf2f(Res[row * N + col]);
          long o = row * N + col;
          if constexpr (EPI == 1 || EPI == 2) {
            OutA[o] = f2bf(t);
            OutB[o] = f2bf(fmaxf(t, 0.f));
          }
          if constexpr (EPI == 4) OutA[o] = f2bf(t);
          if constexpr (EPI == 5) OutF[o] = 1.f / (1.f + expf(-t));
        }
      }
    }
  }
}

// split-K reduce for G1: h1 = relu(bn(p0+p1 + bias)), fixed M=4096, N=1024, S=2
__global__ __launch_bounds__(256) void splitk_bn_relu_k(
    const float* __restrict__ P, const float* __restrict__ bias,
    const float* __restrict__ g, const float* __restrict__ be,
    const float* __restrict__ m, const float* __restrict__ v,
    ushort_t* __restrict__ out) {
  int i = blockIdx.x * 256 + threadIdx.x;     // float4 index
  float4 a = ((const float4*)P)[i];
  float4 b = ((const float4*)(P + 4194304))[i];
  int col = (i << 2) & 1023;
  float t[4] = {a.x + b.x, a.y + b.y, a.z + b.z, a.w + b.w};
  ushort4 o;
  ushort_t* op = (ushort_t*)&o;
#pragma unroll
  for (int k = 0; k < 4; k++) {
    int c = col + k;
    float s = rsqrtf(v[c] + 1e-5f);
    float sA = g[c] * s;
    float val = (t[k] + bias[c] - m[c]) * sA + be[c];
    op[k] = f2bf(fmaxf(val, 0.f));
  }
  ((ushort4*)out)[i] = o;
}

// ---------------- VQ gather / loss partials / histogram ----------------
__global__ __launch_bounds__(256) void vq_finalize_k(
    const unsigned long long* __restrict__ keys, const float* __restrict__ cb,
    const ushort_t* __restrict__ zb, ushort_t* __restrict__ hq, ushort_t* __restrict__ hqr,
    float* __restrict__ hist, float* __restrict__ partial) {
  int row = blockIdx.x, t = threadIdx.x;
  unsigned long long k = keys[row];
  int j = (int)(k & 0xffffffffull);
  float q = cb[j * 256 + t];
  float z = bf2f(zb[(size_t)row * 256 + t]);
  float d = (q - z) * (q - z);
  for (int o = 32; o; o >>= 1) d += __shfl_down(d, o);
  __shared__ float red[4];
  if ((t & 63) == 0) red[t >> 6] = d;
  __syncthreads();
  hq[(size_t)row * 256 + t] = f2bf(q);
  hqr[(size_t)row * 256 + t] = f2bf(fmaxf(q, 0.f));
  if (t == 0) {
    partial[row] = red[0] + red[1] + red[2] + red[3];
    atomicAdd(&hist[j], 1.0f);
  }
}

__global__ __launch_bounds__(256) void finalize_out_k(const float* __restrict__ hist,
                                                      const float* __restrict__ partial,
                                                      float* __restrict__ out) {
  int t = threadIdx.x;
  float ls = 0.f, e = 0.f;
  for (int i = t; i < 16384; i += 256) ls += partial[i];
  for (int i = t; i < 4096; i += 256) {
    float p = hist[i] * (1.f / 16384.f);
    e += p * logf(p + 1e-10f);
  }
  for (int o = 32; o; o >>= 1) {
    ls += __shfl_down(ls, o);
    e += __shfl_down(e, o);
  }
  __shared__ float r1[4], r2[4];
  if ((t & 63) == 0) { r1[t >> 6] = ls; r2[t >> 6] = e; }
  __syncthreads();
  if (t == 0) {
    // loss = (1+CC)*mean((q-z)^2); stop_gradient makes both terms equal in value
    out[0] = (r1[0] + r1[1] + r1[2] + r1[3]) * (1.25f / 4194304.f);
    out[1 + 33554432] = expf(-(r2[0] + r2[1] + r2[2] + r2[3]));
  }
}

// ---------------- launch ----------------
extern "C" void kernel_launch(void* const* d_in, const int* in_sizes, int n_in,
                              void* d_out, int out_size, void* d_ws, size_t ws_size,
                              hipStream_t stream) {
  (void)in_sizes; (void)n_in; (void)out_size; (void)ws_size;
  const float* x    = (const float*)d_in[0];
  const float* W1   = (const float*)d_in[1];
  const float* b1   = (const float*)d_in[2];
  const float* bn1g = (const float*)d_in[3];
  const float* bn1b = (const float*)d_in[4];
  const float* bn1m = (const float*)d_in[5];
  const float* bn1v = (const float*)d_in[6];
  const float* W2   = (const float*)d_in[7];
  const float* b2   = (const float*)d_in[8];
  const float* rbW  = (const float*)d_in[9];
  const float* rbB  = (const float*)d_in[10];
  const float* rbG  = (const float*)d_in[11];
  const float* rbBe = (const float*)d_in[12];
  const float* rbM  = (const float*)d_in[13];
  const float* rbV  = (const float*)d_in[14];
  const float* cb   = (const float*)d_in[15];
  const float* decW = (const float*)d_in[16];
  const float* decB = (const float*)d_in[17];
  float* out = (float*)d_out;

  char* w = (char*)d_ws;
  size_t off = 0;
  auto take = [&](size_t bytes) -> char* {
    char* p = w + off;
    off += (bytes + 255) & ~((size_t)255);
    return p;
  };
  ushort_t* xb    = (ushort_t*)take((size_t)4096 * 8192 * 2);
  ushort_t* w1t   = (ushort_t*)take((size_t)1024 * 8192 * 2);
  ushort_t* w2t   = (ushort_t*)take((size_t)1024 * 1024 * 2);
  ushort_t* rbwt  = (ushort_t*)take((size_t)5 * 1024 * 1024 * 2);
  ushort_t* decwt = (ushort_t*)take((size_t)8192 * 1024 * 2);
  ushort_t* cbb   = (ushort_t*)take((size_t)4096 * 256 * 2);
  float* cnorm    = (float*)take(4096 * 4);
  unsigned long long* keys = (unsigned long long*)take(16384 * 8);
  float* hist     = (float*)take(4096 * 4);
  float* partial  = (float*)take(16384 * 4);
  ushort_t* bufA  = (ushort_t*)take((size_t)4096 * 1024 * 2);
  ushort_t* bufB  = (ushort_t*)take((size_t)4096 * 1024 * 2);
  ushort_t* bufC  = (ushort_t*)take((size_t)4096 * 1024 * 2);
  ushort_t* bufD  = (ushort_t*)take((size_t)4096 * 1024 * 2);
  float* pbuf     = (float*)take((size_t)2 * 4096 * 1024 * 4);   // split-K partials

  (void)hipMemsetAsync(keys, 0xFF, 16384 * 8, stream);
  (void)hipMemsetAsync(hist, 0, 4096 * 4, stream);

  // prep: bf16 conversions (+ weight transposes to [N][K])
  cvt_bf16_k<<<32768, 256, 0, stream>>>(x, xb, 33554432 / 4);
  transpose_k<<<dim3(32, 256), dim3(32, 8), 0, stream>>>(W1, w1t, 8192, 1024);
  transpose_k<<<dim3(32, 32), dim3(32, 8), 0, stream>>>(W2, w2t, 1024, 1024);
  for (int i = 0; i < 5; i++)
    transpose_k<<<dim3(32, 32), dim3(32, 8), 0, stream>>>(
        rbW + (size_t)i * 1024 * 1024, rbwt + (size_t)i * 1024 * 1024, 1024, 1024);
  transpose_k<<<dim3(256, 32), dim3(32, 8), 0, stream>>>(decW, decwt, 1024, 8192);
  cvt_codebook_k<<<4096, 256, 0, stream>>>(cb, cbb, cnorm);

  const ushort_t* nu = nullptr;
  ushort_t* nuo = nullptr;
  const float* nf = nullptr;
  float* nfo = nullptr;
  unsigned long long* nk = nullptr;

  // G1: split-K=2 partials (x@W1), then reduce: h1 = relu(bn1(. + b1)) -> bufA
  gemm_k<7, 128, 128><<<dim3(8, 32, 2), 256, 0, stream>>>(
      xb, w1t, 4096, 1024, 8192, 4096, nf, nf, nf, nf, nf, nu, nuo, nuo, pbuf, nf, nk);
  splitk_bn_relu_k<<<4096, 256, 0, stream>>>(pbuf, b1, bn1g, bn1b, bn1m, bn1v, bufA);
  // G2: h2 = h1@W2 + b2                     -> bufB (raw), bufC (relu)
  gemm_k<1, 64, 128><<<dim3(8, 64), 256, 0, stream>>>(
      bufA, w2t, 4096, 1024, 1024, 1024, b2, nf, nf, nf, nf, nu, bufB, bufC, nfo, nf, nk);
  // G3: z1 = h2 + bn0(relu(h2)@W0 + b0)     -> bufA (raw), bufD (relu)
  gemm_k<2, 64, 128><<<dim3(8, 64), 256, 0, stream>>>(
      bufC, rbwt, 4096, 1024, 1024, 1024, rbB, rbG, rbBe, rbM, rbV, bufB, bufA, bufD, nfo, nf, nk);
  // G4: z  = z1 + bn1(relu(z1)@W1 + b1)     -> bufB
  gemm_k<4, 64, 128><<<dim3(8, 64), 256, 0, stream>>>(
      bufD, rbwt + 1 * 1048576, 4096, 1024, 1024, 1024, rbB + 1024, rbG + 1024, rbBe + 1024,
      rbM + 1024, rbV + 1024, bufA, bufB, nuo, nfo, nf, nk);
  // VQ: argmin_j |z_i - c_j|^2 over flat [16384 x 256]
  gemm_k<6, 128, 128><<<dim3(32, 128), 256, 0, stream>>>(
      bufB, cbb, 16384, 4096, 256, 256, nf, nf, nf, nf, nf, nu, nuo, nuo, nfo, cnorm, keys);
  // gather + loss partials + histogram      -> bufC (hq), bufD (relu hq)
  vq_finalize_k<<<16384, 256, 0, stream>>>(keys, cb, bufB, bufC, bufD, hist, partial);
  // G5: d1 = hq + bn2(relu(hq)@W2 + b2)     -> bufA (raw), bufB (relu)
  gemm_k<2, 64, 128><<<dim3(8, 64), 256, 0, stream>>>(
      bufD, rbwt + 2 * 1048576, 4096, 1024, 1024, 1024, rbB + 2048, rbG + 2048, rbBe + 2048,
      rbM + 2048, rbV + 2048, bufC, bufA, bufB, nfo, nf, nk);
  // G6: d2                                   -> bufC (raw), bufD (relu)
  gemm_k<2, 64, 128><<<dim3(8, 64), 256, 0, stream>>>(
      bufB, rbwt + 3 * 1048576, 4096, 1024, 1024, 1024, rbB + 3072, rbG + 3072, rbBe + 3072,
      rbM + 3072, rbV + 3072, bufA, bufC, bufD, nfo, nf, nk);
  // G7: d3                                   -> bufA
  gemm_k<4, 64, 128><<<dim3(8, 64), 256, 0, stream>>>(
      bufD, rbwt + 4 * 1048576, 4096, 1024, 1024, 1024, rbB + 4096, rbG + 4096, rbBe + 4096,
      rbM + 4096, rbV + 4096, bufC, bufA, nuo, nfo, nf, nk);
  // G8: x_recon = sigmoid(d3@decW + decB)   -> out[1..]
  gemm_k<5, 128, 128><<<dim3(64, 32), 256, 0, stream>>>(
      bufA, decwt, 4096, 8192, 1024, 1024, decB, nf, nf, nf, nf, nu, nuo, nuo, out + 1, nf, nk);
  // loss (out[0]) and perplexity (out[33554433])
  finalize_out_k<<<1, 256, 0, stream>>>(hist, partial, out);
}

// Round 3
// 757.311 us; speedup vs baseline: 1.1621x; 1.0439x over previous
//
#include <hip/hip_runtime.h>

typedef unsigned short ushort_t;
typedef __attribute__((ext_vector_type(8))) __bf16 bf16x8;
typedef __attribute__((ext_vector_type(4))) float f32x4;

__device__ __forceinline__ ushort_t f2bf(float f) {
  unsigned u = __float_as_uint(f);
  u = u + 0x7FFFu + ((u >> 16) & 1u);   // round-to-nearest-even
  return (ushort_t)(u >> 16);
}
__device__ __forceinline__ float bf2f(ushort_t h) {
  return __uint_as_float(((unsigned)h) << 16);
}

// async global->LDS, 16B per lane. LDS dest = wave-uniform base + lane*16.
__device__ __forceinline__ void async_copy16(ushort_t* lds, const ushort_t* g) {
  __builtin_amdgcn_global_load_lds(
      (__attribute__((address_space(1))) void*)const_cast<ushort_t*>(g),
      (__attribute__((address_space(3))) void*)lds, 16, 0, 0);
}

// ---------------- conversion / prep kernels ----------------

__global__ __launch_bounds__(256) void cvt_bf16_k(const float* __restrict__ in,
                                                  ushort_t* __restrict__ outp, int n4) {
  int i = blockIdx.x * blockDim.x + threadIdx.x;
  if (i >= n4) return;
  float4 v = ((const float4*)in)[i];
  ushort4 o;
  o.x = f2bf(v.x); o.y = f2bf(v.y); o.z = f2bf(v.z); o.w = f2bf(v.w);
  ((ushort4*)outp)[i] = o;
}

// W[Kd][Nd] f32 -> Wt[Nd][Kd] bf16; grid.z batches layers of stride Kd*Nd
__global__ __launch_bounds__(256) void transpose_k(const float* __restrict__ W,
                                                   ushort_t* __restrict__ Wt, int Kd, int Nd) {
  __shared__ float tile[32][33];
  size_t lay = (size_t)blockIdx.z * Kd * Nd;
  const float* Wp = W + lay;
  ushort_t* Wtp = Wt + lay;
  int n0 = blockIdx.x * 32, k0 = blockIdx.y * 32;
  int tx = threadIdx.x, ty = threadIdx.y;   // (32,8)
#pragma unroll
  for (int i = 0; i < 4; i++)
    tile[ty + i * 8][tx] = Wp[(size_t)(k0 + ty + i * 8) * Nd + n0 + tx];
  __syncthreads();
#pragma unroll
  for (int i = 0; i < 4; i++)
    Wtp[(size_t)(n0 + ty + i * 8) * Kd + k0 + tx] = f2bf(tile[tx][ty + i * 8]);
}

// codebook [4096][256]: bf16 copy + fp32 row norms
__global__ __launch_bounds__(256) void cvt_codebook_k(const float* __restrict__ cb,
                                                      ushort_t* __restrict__ cbb,
                                                      float* __restrict__ cnorm) {
  int j = blockIdx.x, t = threadIdx.x;
  float c = cb[j * 256 + t];
  cbb[j * 256 + t] = f2bf(c);
  float s = c * c;
  for (int o = 32; o; o >>= 1) s += __shfl_down(s, o);
  __shared__ float red[4];
  if ((t & 63) == 0) red[t >> 6] = s;
  __syncthreads();
  if (t == 0) cnorm[j] = red[0] + red[1] + red[2] + red[3];
}

// ---------------- main MFMA GEMM ----------------
// C = A(MxK,bf16 rowmajor) * Bt(NxK,bf16 rowmajor)^T, fp32 acc, fused epilogue.
// Tile TMxTN (multiples of 32), 2x2 waves, 16x16x32 MFMA frags.
// EPI: 1=bias->OutA,relu->OutB | 2=res+BN(bias)->OutA,relu->OutB | 4=res+BN(bias)->OutA
//      5=bias+sigmoid->OutF | 6=VQ argmin (cnorm,keys) | 7=raw f32 partial (split-K)
template <int EPI, int TM, int TN>
__global__ __launch_bounds__(256, 4) void gemm_k(
    const ushort_t* __restrict__ A, const ushort_t* __restrict__ Bt,
    int M, int N, int K, int KS,
    const float* __restrict__ bias,
    const float* __restrict__ bng, const float* __restrict__ bnbeta,
    const float* __restrict__ bnm, const float* __restrict__ bnv,
    const ushort_t* __restrict__ Res,
    ushort_t* __restrict__ OutA, ushort_t* __restrict__ OutB,
    float* __restrict__ OutF,
    const float* __restrict__ cnorm, unsigned long long* __restrict__ keys) {
  constexpr int FI = TM / 32, FJ = TN / 32;   // frags per wave (2x2 wave grid)
  __shared__ alignas(16) ushort_t As[TM * 64];
  __shared__ alignas(16) ushort_t Bs[TN * 64];
  const int tid = threadIdx.x;
  const int wave = tid >> 6, lane = tid & 63;
  const int quad = lane >> 4, l16 = lane & 15;
  const int wm = wave >> 1, wn = wave & 1;
  const int m0 = blockIdx.y * TM, n0 = blockIdx.x * TN;

  f32x4 acc[FI][FJ];
#pragma unroll
  for (int i = 0; i < FI; i++)
#pragma unroll
    for (int j = 0; j < FJ; j++) acc[i][j] = f32x4{0.f, 0.f, 0.f, 0.f};

  // staging geometry: inst i covers rows i*32 + wave*8 + lane/8, chunk (lane&7)^(row&7)
  const int srow = (wave << 3) + (lane >> 3);           // row within the 32-row group
  const int schunk = (lane & 7) ^ (lane >> 3);          // XOR-swizzled 8-elem chunk
  const long aoff = (long)(m0 + srow) * K + (schunk << 3);
  const long boff = (long)(n0 + srow) * K + (schunk << 3);

  const int kbeg = blockIdx.z * KS, kend = kbeg + KS;
  for (int k0 = kbeg; k0 < kend; k0 += 64) {
#pragma unroll
    for (int i = 0; i < TM / 32; i++)
      async_copy16(&As[(i * 32 + wave * 8) * 64], A + aoff + (long)i * 32 * K + k0);
#pragma unroll
    for (int i = 0; i < TN / 32; i++)
      async_copy16(&Bs[(i * 32 + wave * 8) * 64], Bt + boff + (long)i * 32 * K + k0);
    __syncthreads();   // compiler drains vmcnt before s_barrier
#pragma unroll
    for (int kk = 0; kk < 2; kk++) {
      bf16x8 af[FI], bfr[FJ];
      const int ca = ((kk * 4 + quad) ^ (l16 & 7)) << 3;   // de-swizzle
#pragma unroll
      for (int i = 0; i < FI; i++)
        af[i] = *(const bf16x8*)&As[(wm * (TM / 2) + i * 16 + l16) * 64 + ca];
#pragma unroll
      for (int j = 0; j < FJ; j++)
        bfr[j] = *(const bf16x8*)&Bs[(wn * (TN / 2) + j * 16 + l16) * 64 + ca];
#pragma unroll
      for (int i = 0; i < FI; i++)
#pragma unroll
        for (int j = 0; j < FJ; j++)
          acc[i][j] = __builtin_amdgcn_mfma_f32_16x16x32_bf16(af[i], bfr[j], acc[i][j], 0, 0, 0);
    }
    __syncthreads();
  }

  if constexpr (EPI == 6) {
    // score_j = |c_j|^2 - 2*z.c_j  (row-constant |z|^2 dropped); argmin w/ lowest-index ties
#pragma unroll
    for (int i = 0; i < FI; i++) {
#pragma unroll
      for (int r = 0; r < 4; r++) {
        int row = m0 + wm * (TM / 2) + i * 16 + quad * 4 + r;
        unsigned long long best = ~0ull;
#pragma unroll
        for (int j = 0; j < FJ; j++) {
          int col = n0 + wn * (TN / 2) + j * 16 + l16;
          float sc = cnorm[col] - 2.f * acc[i][j][r];
          unsigned ub = __float_as_uint(sc);
          ub = (ub & 0x80000000u) ? ~ub : (ub | 0x80000000u);   // sortable float
          unsigned long long key = ((unsigned long long)ub << 32) | (unsigned)col;
          if (key < best) best = key;
        }
#pragma unroll
        for (int o = 1; o < 16; o <<= 1) {
          unsigned long long other = __shfl_xor(best, o, 16);
          if (other < best) best = other;
        }
        if (l16 == 0) atomicMin(&keys[row], best);
      }
    }
    return;
  } else if constexpr (EPI == 7) {
    float* dst = OutF + (size_t)blockIdx.z * (size_t)M * N;
#pragma unroll
    for (int j = 0; j < FJ; j++) {
      int col = n0 + wn * (TN / 2) + j * 16 + l16;
#pragma unroll
      for (int i = 0; i < FI; i++)
#pragma unroll
        for (int r = 0; r < 4; r++) {
          long row = m0 + wm * (TM / 2) + i * 16 + quad * 4 + r;
          dst[row * N + col] = acc[i][j][r];
        }
    }
  } else {
    constexpr bool HAS_BN = (EPI == 2 || EPI == 4);
    constexpr bool HAS_RES = (EPI == 2 || EPI == 4);
#pragma unroll
    for (int j = 0; j < FJ; j++) {
      int col = n0 + wn * (TN / 2) + j * 16 + l16;
      float bi = bias[col];
      float sA = 1.f, sB = 0.f;
      if constexpr (HAS_BN) {
        float s = rsqrtf(bnv[col] + 1e-5f);
        sA = bng[col] * s;
        sB = bnbeta[col] - bnm[col] * sA;
      }
#pragma unroll
      for (int i = 0; i < FI; i++) {
#pragma unroll
        for (int r = 0; r < 4; r++) {
          long row = m0 + wm * (TM / 2) + i * 16 + quad * 4 + r;
          float t = acc[i][j][r] + bi;
          if constexpr (HAS_BN) t = t * sA + sB;
          if constexpr (HAS_RES) t += bf2f(Res[row * N + col]);
          long o = row * N + col;
          if constexpr (EPI == 1 || EPI == 2) {
            OutA[o] = f2bf(t);
            OutB[o] = f2bf(fmaxf(t, 0.f));
          }
          if constexpr (EPI == 4) OutA[o] = f2bf(t);
          if constexpr (EPI == 5) OutF[o] = 1.f / (1.f + expf(-t));
        }
      }
    }
  }
}

// split-K reduce for G1: h1 = relu(bn(p0+p1 + bias)), fixed M=4096, N=1024, S=2
__global__ __launch_bounds__(256) void splitk_bn_relu_k(
    const float* __restrict__ P, const float* __restrict__ bias,
    const float* __restrict__ g, const float* __restrict__ be,
    const float* __restrict__ m, const float* __restrict__ v,
    ushort_t* __restrict__ out) {
  int i = blockIdx.x * 256 + threadIdx.x;     // float4 index
  float4 a = ((const float4*)P)[i];
  float4 b = ((const float4*)(P + 4194304))[i];
  int col = (i << 2) & 1023;
  float t[4] = {a.x + b.x, a.y + b.y, a.z + b.z, a.w + b.w};
  ushort4 o;
  ushort_t* op = (ushort_t*)&o;
#pragma unroll
  for (int k = 0; k < 4; k++) {
    int c = col + k;
    float s = rsqrtf(v[c] + 1e-5f);
    float sA = g[c] * s;
    float val = (t[k] + bias[c] - m[c]) * sA + be[c];
    op[k] = f2bf(fmaxf(val, 0.f));
  }
  ((ushort4*)out)[i] = o;
}

// ---------------- VQ gather / loss partials / histogram ----------------
__global__ __launch_bounds__(256) void vq_finalize_k(
    const unsigned long long* __restrict__ keys, const float* __restrict__ cb,
    const ushort_t* __restrict__ zb, ushort_t* __restrict__ hq, ushort_t* __restrict__ hqr,
    float* __restrict__ hist, float* __restrict__ partial) {
  int row = blockIdx.x, t = threadIdx.x;
  unsigned long long k = keys[row];
  int j = (int)(k & 0xffffffffull);
  float q = cb[j * 256 + t];
  float z = bf2f(zb[(size_t)row * 256 + t]);
  float d = (q - z) * (q - z);
  for (int o = 32; o; o >>= 1) d += __shfl_down(d, o);
  __shared__ float red[4];
  if ((t & 63) == 0) red[t >> 6] = d;
  __syncthreads();
  hq[(size_t)row * 256 + t] = f2bf(q);
  hqr[(size_t)row * 256 + t] = f2bf(fmaxf(q, 0.f));
  if (t == 0) {
    partial[row] = red[0] + red[1] + red[2] + red[3];
    atomicAdd(&hist[j], 1.0f);
  }
}

__global__ __launch_bounds__(256) void finalize_out_k(const float* __restrict__ hist,
                                                      const float* __restrict__ partial,
                                                      float* __restrict__ out) {
  int t = threadIdx.x;
  float ls = 0.f, e = 0.f;
  for (int i = t; i < 16384; i += 256) ls += partial[i];
  for (int i = t; i < 4096; i += 256) {
    float p = hist[i] * (1.f / 16384.f);
    e += p * logf(p + 1e-10f);
  }
  for (int o = 32; o; o >>= 1) {
    ls += __shfl_down(ls, o);
    e += __shfl_down(e, o);
  }
  __shared__ float r1[4], r2[4];
  if ((t & 63) == 0) { r1[t >> 6] = ls; r2[t >> 6] = e; }
  __syncthreads();
  if (t == 0) {
    // loss = (1+CC)*mean((q-z)^2); stop_gradient makes both terms equal in value
    out[0] = (r1[0] + r1[1] + r1[2] + r1[3]) * (1.25f / 4194304.f);
    out[1 + 33554432] = expf(-(r2[0] + r2[1] + r2[2] + r2[3]));
  }
}

// ---------------- launch ----------------
extern "C" void kernel_launch(void* const* d_in, const int* in_sizes, int n_in,
                              void* d_out, int out_size, void* d_ws, size_t ws_size,
                              hipStream_t stream) {
  (void)in_sizes; (void)n_in; (void)out_size; (void)ws_size;
  const float* x    = (const float*)d_in[0];
  const float* W1   = (const float*)d_in[1];
  const float* b1   = (const float*)d_in[2];
  const float* bn1g = (const float*)d_in[3];
  const float* bn1b = (const float*)d_in[4];
  const float* bn1m = (const float*)d_in[5];
  const float* bn1v = (const float*)d_in[6];
  const float* W2   = (const float*)d_in[7];
  const float* b2   = (const float*)d_in[8];
  const float* rbW  = (const float*)d_in[9];
  const float* rbB  = (const float*)d_in[10];
  const float* rbG  = (const float*)d_in[11];
  const float* rbBe = (const float*)d_in[12];
  const float* rbM  = (const float*)d_in[13];
  const float* rbV  = (const float*)d_in[14];
  const float* cb   = (const float*)d_in[15];
  const float* decW = (const float*)d_in[16];
  const float* decB = (const float*)d_in[17];
  float* out = (float*)d_out;

  char* w = (char*)d_ws;
  size_t off = 0;
  auto take = [&](size_t bytes) -> char* {
    char* p = w + off;
    off += (bytes + 255) & ~((size_t)255);
    return p;
  };
  ushort_t* xb    = (ushort_t*)take((size_t)4096 * 8192 * 2);
  ushort_t* w1t   = (ushort_t*)take((size_t)1024 * 8192 * 2);
  ushort_t* w2t   = (ushort_t*)take((size_t)1024 * 1024 * 2);
  ushort_t* rbwt  = (ushort_t*)take((size_t)5 * 1024 * 1024 * 2);
  ushort_t* decwt = (ushort_t*)take((size_t)8192 * 1024 * 2);
  ushort_t* cbb   = (ushort_t*)take((size_t)4096 * 256 * 2);
  float* cnorm    = (float*)take(4096 * 4);
  unsigned long long* keys = (unsigned long long*)take(16384 * 8);
  float* hist     = (float*)take(4096 * 4);
  float* partial  = (float*)take(16384 * 4);
  ushort_t* bufA  = (ushort_t*)take((size_t)4096 * 1024 * 2);
  ushort_t* bufB  = (ushort_t*)take((size_t)4096 * 1024 * 2);
  ushort_t* bufC  = (ushort_t*)take((size_t)4096 * 1024 * 2);
  ushort_t* bufD  = (ushort_t*)take((size_t)4096 * 1024 * 2);
  float* pbuf     = (float*)take((size_t)2 * 4096 * 1024 * 4);   // split-K partials

  (void)hipMemsetAsync(keys, 0xFF, 16384 * 8, stream);
  (void)hipMemsetAsync(hist, 0, 4096 * 4, stream);

  // prep: bf16 conversions (+ weight transposes to [N][K])
  cvt_bf16_k<<<32768, 256, 0, stream>>>(x, xb, 33554432 / 4);
  transpose_k<<<dim3(32, 256), dim3(32, 8), 0, stream>>>(W1, w1t, 8192, 1024);
  transpose_k<<<dim3(32, 32), dim3(32, 8), 0, stream>>>(W2, w2t, 1024, 1024);
  transpose_k<<<dim3(32, 32, 5), dim3(32, 8), 0, stream>>>(rbW, rbwt, 1024, 1024);
  transpose_k<<<dim3(256, 32), dim3(32, 8), 0, stream>>>(decW, decwt, 1024, 8192);
  cvt_codebook_k<<<4096, 256, 0, stream>>>(cb, cbb, cnorm);

  const ushort_t* nu = nullptr;
  ushort_t* nuo = nullptr;
  const float* nf = nullptr;
  float* nfo = nullptr;
  unsigned long long* nk = nullptr;

  // G1: split-K=2 partials (x@W1) w/ 64x128 tile, grid 1024 = 4 blocks/CU,
  //     then reduce: h1 = relu(bn1(. + b1)) -> bufA
  gemm_k<7, 64, 128><<<dim3(8, 64, 2), 256, 0, stream>>>(
      xb, w1t, 4096, 1024, 8192, 4096, nf, nf, nf, nf, nf, nu, nuo, nuo, pbuf, nf, nk);
  splitk_bn_relu_k<<<4096, 256, 0, stream>>>(pbuf, b1, bn1g, bn1b, bn1m, bn1v, bufA);
  // G2: h2 = h1@W2 + b2                     -> bufB (raw), bufC (relu)
  gemm_k<1, 64, 64><<<dim3(16, 64), 256, 0, stream>>>(
      bufA, w2t, 4096, 1024, 1024, 1024, b2, nf, nf, nf, nf, nu, bufB, bufC, nfo, nf, nk);
  // G3: z1 = h2 + bn0(relu(h2)@W0 + b0)     -> bufA (raw), bufD (relu)
  gemm_k<2, 64, 64><<<dim3(16, 64), 256, 0, stream>>>(
      bufC, rbwt, 4096, 1024, 1024, 1024, rbB, rbG, rbBe, rbM, rbV, bufB, bufA, bufD, nfo, nf, nk);
  // G4: z  = z1 + bn1(relu(z1)@W1 + b1)     -> bufB
  gemm_k<4, 64, 64><<<dim3(16, 64), 256, 0, stream>>>(
      bufD, rbwt + 1 * 1048576, 4096, 1024, 1024, 1024, rbB + 1024, rbG + 1024, rbBe + 1024,
      rbM + 1024, rbV + 1024, bufA, bufB, nuo, nfo, nf, nk);
  // VQ: argmin_j |z_i - c_j|^2 over flat [16384 x 256]
  gemm_k<6, 128, 128><<<dim3(32, 128), 256, 0, stream>>>(
      bufB, cbb, 16384, 4096, 256, 256, nf, nf, nf, nf, nf, nu, nuo, nuo, nfo, cnorm, keys);
  // gather + loss partials + histogram      -> bufC (hq), bufD (relu hq)
  vq_finalize_k<<<16384, 256, 0, stream>>>(keys, cb, bufB, bufC, bufD, hist, partial);
  // G5: d1 = hq + bn2(relu(hq)@W2 + b2)     -> bufA (raw), bufB (relu)
  gemm_k<2, 64, 64><<<dim3(16, 64), 256, 0, stream>>>(
      bufD, rbwt + 2 * 1048576, 4096, 1024, 1024, 1024, rbB + 2048, rbG + 2048, rbBe + 2048,
      rbM + 2048, rbV + 2048, bufC, bufA, bufB, nfo, nf, nk);
  // G6: d2                                   -> bufC (raw), bufD (relu)
  gemm_k<2, 64, 64><<<dim3(16, 64), 256, 0, stream>>>(
      bufB, rbwt + 3 * 1048576, 4096, 1024, 1024, 1024, rbB + 3072, rbG + 3072, rbBe + 3072,
      rbM + 3072, rbV + 3072, bufA, bufC, bufD, nfo, nf, nk);
  // G7: d3                                   -> bufA
  gemm_k<4, 64, 64><<<dim3(16, 64), 256, 0, stream>>>(
      bufD, rbwt + 4 * 1048576, 4096, 1024, 1024, 1024, rbB + 4096, rbG + 4096, rbBe + 4096,
      rbM + 4096, rbV + 4096, bufC, bufA, nuo, nfo, nf, nk);
  // G8: x_recon = sigmoid(d3@decW + decB)   -> out[1..]
  gemm_k<5, 128, 128><<<dim3(64, 32), 256, 0, stream>>>(
      bufA, decwt, 4096, 8192, 1024, 1024, decB, nf, nf, nf, nf, nu, nuo, nuo, out + 1, nf, nk);
  // loss (out[0]) and perplexity (out[33554433])
  finalize_out_k<<<1, 256, 0, stream>>>(hist, partial, out);
}